// Round 8
// baseline (227.357 us; speedup 1.0000x reference)
//
#include <hip/hip_runtime.h>
#include <hip/hip_fp16.h>

#define N_NODES 100000
#define N_EDGES 3200000
#define IN_DIM 6
#define HID_DIM 32
#define LAT_DIM 16

#define NPB 128                      // nodes per bucket (dst >> 7)
#define NB 782                       // ceil(100000 / 128)
#define CAP 4800                     // bucket segment capacity (mean 4092, sigma 64)
#define AB_BLOCKS 512
#define CH ((N_EDGES + AB_BLOCKS - 1) / AB_BLOCKS)   // 6250 edges per place block
#define PL_T 512                     // threads in k_bplace

// ---------------- init bucket cursors to segment bases ----------------
__global__ void k_init(int* __restrict__ bcur) {
    int i = blockIdx.x * blockDim.x + threadIdx.x;
    if (i < NB) bcur[i] = i * CAP;
}

// ---------------- place edges: LDS counting-sort staging -> coalesced nt writes ----------------
__global__ void __launch_bounds__(PL_T) k_bplace(const int* __restrict__ src,
                                                 const int* __restrict__ dst,
                                                 int* __restrict__ bcur,
                                                 int* __restrict__ bedge, int E) {
    __shared__ int hist[NB];
    __shared__ int lbase[NB];
    __shared__ int gbase[NB];
    __shared__ int cur[NB];
    __shared__ int part[PL_T];
    __shared__ int stage[CH];
    __shared__ unsigned short sbkt[CH];
    int t = threadIdx.x;
    for (int i = t; i < NB; i += PL_T) { hist[i] = 0; cur[i] = 0; }
    __syncthreads();
    int beg = blockIdx.x * CH, end = min(beg + CH, E);
    // pass 1: block-local histogram (nt: stream-once data)
    for (int e = beg + t; e < end; e += PL_T)
        atomicAdd(&hist[__builtin_nontemporal_load(dst + e) >> 7], 1);
    __syncthreads();
    // exclusive scan of hist -> lbase (2 elems/thread)
    int i0 = 2 * t;
    int a = (i0 < NB) ? hist[i0] : 0;
    int b = (i0 + 1 < NB) ? hist[i0 + 1] : 0;
    part[t] = a + b;
    __syncthreads();
    for (int off = 1; off < PL_T; off <<= 1) {
        int v = (t >= off) ? part[t - off] : 0;
        __syncthreads();
        part[t] += v;
        __syncthreads();
    }
    int ex = (t == 0) ? 0 : part[t - 1];
    if (i0 < NB) lbase[i0] = ex;
    if (i0 + 1 < NB) lbase[i0 + 1] = ex + a;
    __syncthreads();
    // reserve global ranges per bucket (bcur pre-seeded to b*CAP)
    for (int i = t; i < NB; i += PL_T)
        gbase[i] = hist[i] ? atomicAdd(&bcur[i], hist[i]) : 0;
    __syncthreads();
    // pass 2: scatter into LDS staging, sorted by bucket
    for (int e = beg + t; e < end; e += PL_T) {
        int d = __builtin_nontemporal_load(dst + e);
        int s = __builtin_nontemporal_load(src + e);
        int bkt = d >> 7;
        int r = atomicAdd(&cur[bkt], 1);
        int pos = lbase[bkt] + r;
        stage[pos] = (s << 7) | (d & (NPB - 1));
        sbkt[pos] = (unsigned short)bkt;
    }
    __syncthreads();
    // stream out: coalesced within bucket runs, nt (consumed next kernel, don't cache)
    int total = end - beg;
    for (int j = t; j < total; j += PL_T) {
        int bkt = sbkt[j];
        __builtin_nontemporal_store(stage[j], bedge + gbase[bkt] + (j - lbase[bkt]));
    }
}

// ---------------- per-bucket counting sort -> (beg,end) CSR + dinv + xs(fp16) ----------------
__global__ void k_sort(const int* __restrict__ bcur, const int* __restrict__ bedge,
                       const float* __restrict__ x, int2* __restrict__ rowse,
                       int* __restrict__ perm, float* __restrict__ dinv,
                       __half* __restrict__ xs, int N) {
    int b = blockIdx.x;
    __shared__ int cnt[NPB], base[NPB], cur[NPB], scn[NPB];
    __shared__ float dvs[NPB];
    int t = threadIdx.x;
    if (t < NPB) cnt[t] = 0;
    __syncthreads();
    int beg = b * CAP, end = bcur[b];
    for (int k = beg + t; k < end; k += blockDim.x)
        atomicAdd(&cnt[bedge[k] & (NPB - 1)], 1);
    __syncthreads();
    if (t < NPB) scn[t] = cnt[t];
    __syncthreads();
    for (int off = 1; off < NPB; off <<= 1) {
        int v = 0;
        if (t < NPB && t >= off) v = scn[t - off];
        __syncthreads();
        if (t < NPB) scn[t] += v;
        __syncthreads();
    }
    if (t < NPB) {
        int ex = scn[t] - cnt[t];  // exclusive
        base[t] = ex;
        cur[t] = 0;
        int node = (b << 7) + t;
        if (node < N) {
            float dv = rsqrtf((float)(cnt[t] + 1));  // +1 self-loop
            dvs[t] = dv;
            dinv[node] = dv;
            rowse[node] = make_int2(beg + ex, beg + ex + cnt[t]);
        }
    }
    __syncthreads();
    for (int k = beg + t; k < end; k += blockDim.x) {
        int w = bedge[k];
        int dl = w & (NPB - 1);
        int pos = beg + base[dl] + atomicAdd(&cur[dl], 1);
        __builtin_nontemporal_store(w >> 7, perm + pos);  // streamed, re-read next kernels
    }
    // fused: xs[n][d] = fp16(x[n][d] * dinv[n]), padded to 8 halfs (16B rows)
    for (int i = t; i < NPB * 4; i += blockDim.x) {
        int nl = i >> 2, d2 = (i & 3) * 2;
        int node = (b << 7) + nl;
        if (node < N) {
            float dv = dvs[nl];
            float v0 = (d2 < IN_DIM) ? x[(size_t)node * IN_DIM + d2] * dv : 0.f;
            float v1 = (d2 + 1 < IN_DIM) ? x[(size_t)node * IN_DIM + d2 + 1] * dv : 0.f;
            *(__half2*)(xs + (size_t)node * 8 + d2) = __floats2half2_rn(v0, v1);
        }
    }
}

// ---------------- layer 1 fused: aggregate 6-dim (fp16 table) -> W1+relu -> W2 -> h2s (fp16) ----------------
__global__ void __launch_bounds__(256) k_agg1f(const int2* __restrict__ rowse,
                                               const int* __restrict__ perm,
                                               const __half* __restrict__ xs,
                                               const float* __restrict__ dinv,
                                               const float* __restrict__ b1,
                                               const float* __restrict__ W1,
                                               const float* __restrict__ W2,
                                               __half* __restrict__ h2s, int N) {
    __shared__ float w1[IN_DIM * HID_DIM];
    __shared__ float w2[HID_DIM * LAT_DIM];
    __shared__ float bsh[HID_DIM];
    __shared__ float ash[32][HID_DIM + 1];  // +1 pad: avoid bank conflict
    __shared__ float y[32][8];
    int t = threadIdx.x;
    for (int i = t; i < IN_DIM * HID_DIM; i += 256) w1[i] = W1[i];
    for (int i = t; i < HID_DIM * LAT_DIM; i += 256) w2[i] = W2[i];
    if (t < HID_DIM) bsh[t] = b1[t];
    int nl = t >> 3, p = t & 7;
    int node = blockIdx.x * 32 + nl;
    float acc = 0.f;
    if (node < N) {
        int2 se = rowse[node];
        for (int k0 = se.x; k0 < se.y; k0 += 8) {
            int kk = k0 + p;
            int sp = (kk < se.y) ? __builtin_nontemporal_load(perm + kk) : -1;
#pragma unroll
            for (int j = 0; j < 8; j++) {
                int s = __shfl(sp, j, 8);
                if (s >= 0) acc += __half2float(xs[(size_t)s * 8 + p]);  // L2-hot 16B rows
            }
        }
        acc += __half2float(xs[(size_t)node * 8 + p]);  // self-loop
    }
    y[nl][p] = acc;
    __syncthreads();
    float dv = (node < N) ? dinv[node] : 0.f;
    if (node < N) {
        float yy[IN_DIM];
#pragma unroll
        for (int k = 0; k < IN_DIM; k++) yy[k] = y[nl][k];
        int c0 = p * 4;
#pragma unroll
        for (int q = 0; q < 4; q++) {
            float z = 0.f;
#pragma unroll
            for (int k = 0; k < IN_DIM; k++) z += yy[k] * w1[k * HID_DIM + c0 + q];
            ash[nl][c0 + q] = fmaxf(dv * z + bsh[c0 + q], 0.f);
        }
    }
    __syncthreads();
    if (node < N) {
        int c = p * 2;
        float z0 = 0.f, z1 = 0.f;
#pragma unroll
        for (int k = 0; k < HID_DIM; k++) {
            float a = ash[nl][k];
            z0 += a * w2[k * LAT_DIM + c];
            z1 += a * w2[k * LAT_DIM + c + 1];
        }
        __half2 h = __floats2half2_rn(dv * z0, dv * z1);
        *(__half2*)(h2s + (size_t)node * LAT_DIM + c) = h;
    }
}

// ---------------- layer-2 gather-aggregate + bias -> out: 8 lanes/node, fp16 table ----------------
__global__ void k_agg2(const int2* __restrict__ rowse, const int* __restrict__ perm,
                       const __half* __restrict__ h2s, const float* __restrict__ dinv,
                       const float* __restrict__ b2, float* __restrict__ out, int N) {
    int t = blockIdx.x * blockDim.x + threadIdx.x;
    int node = t >> 3, p = t & 7;
    if (node >= N) return;
    int2 se = rowse[node];
    float2 acc = make_float2(0.f, 0.f);
    for (int k0 = se.x; k0 < se.y; k0 += 8) {
        int kk = k0 + p;
        int sp = (kk < se.y) ? __builtin_nontemporal_load(perm + kk) : -1;
#pragma unroll
        for (int j = 0; j < 8; j++) {
            int s = __shfl(sp, j, 8);
            if (s >= 0) {
                __half2 h = *(const __half2*)(h2s + (size_t)s * LAT_DIM + p * 2);
                float2 f = __half22float2(h);
                acc.x += f.x; acc.y += f.y;
            }
        }
    }
    __half2 hh = *(const __half2*)(h2s + (size_t)node * LAT_DIM + p * 2);  // self-loop
    float2 hs = __half22float2(hh);
    float dv = dinv[node];
    float2 bb = *(const float2*)(b2 + p * 2);
    float2 o;
    o.x = dv * (acc.x + hs.x) + bb.x;
    o.y = dv * (acc.y + hs.y) + bb.y;
    *(float2*)(out + (size_t)node * LAT_DIM + p * 2) = o;
}

extern "C" void kernel_launch(void* const* d_in, const int* in_sizes, int n_in,
                              void* d_out, int out_size, void* d_ws, size_t ws_size,
                              hipStream_t stream) {
    const float* x  = (const float*)d_in[0];
    const int*   ei = (const int*)d_in[1];
    const float* W1 = (const float*)d_in[2];
    const float* b1 = (const float*)d_in[3];
    const float* W2 = (const float*)d_in[4];
    const float* b2 = (const float*)d_in[5];
    float* out = (float*)d_out;

    const int N = N_NODES, E = N_EDGES;
    const int* src = ei;       // edge_index[0]
    const int* dst = ei + E;   // edge_index[1]

    // workspace carve (256B aligned)
    char* ws = (char*)d_ws;
    size_t off = 0;
    auto take = [&](size_t bytes) -> void* {
        void* p = ws + off;
        off += (bytes + 255) & ~(size_t)255;
        return p;
    };
    int*    bcur  = (int*)take((size_t)NB * 4);
    int*    bedge = (int*)take((size_t)NB * CAP * 4);
    int*    perm  = (int*)take((size_t)NB * CAP * 4);
    int2*   rowse = (int2*)take((size_t)N * 8);
    float*  dinv  = (float*)take((size_t)N * 4);
    __half* xs    = (__half*)take((size_t)N * 8 * 2);
    __half* h2s   = (__half*)take((size_t)N * LAT_DIM * 2);

    const int B = 256;
    k_init<<<(NB + B - 1) / B, B, 0, stream>>>(bcur);
    k_bplace<<<AB_BLOCKS, PL_T, 0, stream>>>(src, dst, bcur, bedge, E);
    k_sort<<<NB, B, 0, stream>>>(bcur, bedge, x, rowse, perm, dinv, xs, N);
    k_agg1f<<<(N + 31) / 32, B, 0, stream>>>(rowse, perm, xs, dinv, b1, W1, W2, h2s, N);
    k_agg2<<<((N * 8) + B - 1) / B, B, 0, stream>>>(rowse, perm, h2s, dinv, b2, out, N);
}

// Round 9
// 145.202 us; speedup vs baseline: 1.5658x; 1.5658x over previous
//
#include <hip/hip_runtime.h>
#include <hip/hip_fp16.h>

#define N_NODES 100000
#define N_EDGES 3200000
#define IN_DIM 6
#define HID_DIM 32
#define LAT_DIM 16

#define NPB 128                      // nodes per bucket (dst >> 7)
#define NB 782                       // ceil(100000 / 128)
#define CAP 4800                     // bucket segment capacity (mean 4092, sigma 64)
#define AB_BLOCKS 512
#define CH ((N_EDGES + AB_BLOCKS - 1) / AB_BLOCKS)   // 6250 edges per place block
#define PL_T 512                     // threads in k_bplace

// ---------------- init bucket cursors to segment bases ----------------
__global__ void k_init(int* __restrict__ bcur) {
    int i = blockIdx.x * blockDim.x + threadIdx.x;
    if (i < NB) bcur[i] = i * CAP;
}

// ---------------- place edges: LDS counting-sort staging -> coalesced writes ----------------
__global__ void __launch_bounds__(PL_T) k_bplace(const int* __restrict__ src,
                                                 const int* __restrict__ dst,
                                                 int* __restrict__ bcur,
                                                 int* __restrict__ bedge, int E) {
    __shared__ int hist[NB];
    __shared__ int lbase[NB];
    __shared__ int gbase[NB];
    __shared__ int cur[NB];
    __shared__ int part[PL_T];
    __shared__ int stage[CH];
    __shared__ unsigned short sbkt[CH];
    int t = threadIdx.x;
    for (int i = t; i < NB; i += PL_T) { hist[i] = 0; cur[i] = 0; }
    __syncthreads();
    int beg = blockIdx.x * CH, end = min(beg + CH, E);
    // pass 1: block-local histogram (nt loads: stream-once data)
    for (int e = beg + t; e < end; e += PL_T)
        atomicAdd(&hist[__builtin_nontemporal_load(dst + e) >> 7], 1);
    __syncthreads();
    // exclusive scan of hist -> lbase (2 elems/thread)
    int i0 = 2 * t;
    int a = (i0 < NB) ? hist[i0] : 0;
    int b = (i0 + 1 < NB) ? hist[i0 + 1] : 0;
    part[t] = a + b;
    __syncthreads();
    for (int off = 1; off < PL_T; off <<= 1) {
        int v = (t >= off) ? part[t - off] : 0;
        __syncthreads();
        part[t] += v;
        __syncthreads();
    }
    int ex = (t == 0) ? 0 : part[t - 1];
    if (i0 < NB) lbase[i0] = ex;
    if (i0 + 1 < NB) lbase[i0 + 1] = ex + a;
    __syncthreads();
    // reserve global ranges per bucket (bcur pre-seeded to b*CAP)
    for (int i = t; i < NB; i += PL_T)
        gbase[i] = hist[i] ? atomicAdd(&bcur[i], hist[i]) : 0;
    __syncthreads();
    // pass 2: scatter into LDS staging, sorted by bucket
    for (int e = beg + t; e < end; e += PL_T) {
        int d = __builtin_nontemporal_load(dst + e);
        int s = __builtin_nontemporal_load(src + e);
        int bkt = d >> 7;
        int r = atomicAdd(&cur[bkt], 1);
        int pos = lbase[bkt] + r;
        stage[pos] = (s << 7) | (d & (NPB - 1));
        sbkt[pos] = (unsigned short)bkt;
    }
    __syncthreads();
    // stream out: coalesced within bucket runs; REGULAR store (re-read by k_sort via L2)
    int total = end - beg;
    for (int j = t; j < total; j += PL_T) {
        int bkt = sbkt[j];
        bedge[gbase[bkt] + (j - lbase[bkt])] = stage[j];
    }
}

// ---------------- per-bucket counting sort -> (beg,end) CSR + dinv + xs(fp16) ----------------
// perm staged in LDS at sorted position, then streamed out coalesced.
__global__ void __launch_bounds__(256) k_sort(const int* __restrict__ bcur,
                                              const int* __restrict__ bedge,
                                              const float* __restrict__ x,
                                              int2* __restrict__ rowse,
                                              int* __restrict__ perm,
                                              float* __restrict__ dinv,
                                              __half* __restrict__ xs, int N) {
    int b = blockIdx.x;
    __shared__ int cnt[NPB], base[NPB], cur[NPB], scn[NPB];
    __shared__ float dvs[NPB];
    __shared__ int pstage[CAP];  // 19.2 KB
    int t = threadIdx.x;
    if (t < NPB) cnt[t] = 0;
    __syncthreads();
    int beg = b * CAP, end = bcur[b];
    int m = end - beg;
    for (int k = t; k < m; k += blockDim.x)
        atomicAdd(&cnt[bedge[beg + k] & (NPB - 1)], 1);
    __syncthreads();
    if (t < NPB) scn[t] = cnt[t];
    __syncthreads();
    for (int off = 1; off < NPB; off <<= 1) {
        int v = 0;
        if (t < NPB && t >= off) v = scn[t - off];
        __syncthreads();
        if (t < NPB) scn[t] += v;
        __syncthreads();
    }
    if (t < NPB) {
        int ex = scn[t] - cnt[t];  // exclusive
        base[t] = ex;
        cur[t] = 0;
        int node = (b << 7) + t;
        if (node < N) {
            float dv = rsqrtf((float)(cnt[t] + 1));  // +1 self-loop
            dvs[t] = dv;
            dinv[node] = dv;
            rowse[node] = make_int2(beg + ex, beg + ex + cnt[t]);
        }
    }
    __syncthreads();
    // scatter into LDS staging (cheap), not global
    for (int k = t; k < m; k += blockDim.x) {
        int w = bedge[beg + k];
        int dl = w & (NPB - 1);
        int pos = base[dl] + atomicAdd(&cur[dl], 1);
        pstage[pos] = w >> 7;
    }
    __syncthreads();
    // coalesced stream-out
    for (int k = t; k < m; k += blockDim.x)
        perm[beg + k] = pstage[k];
    // fused: xs[n][d] = fp16(x[n][d] * dinv[n]), padded to 8 halfs (16B rows)
    for (int i = t; i < NPB * 4; i += blockDim.x) {
        int nl = i >> 2, d2 = (i & 3) * 2;
        int node = (b << 7) + nl;
        if (node < N) {
            float dv = dvs[nl];
            float v0 = (d2 < IN_DIM) ? x[(size_t)node * IN_DIM + d2] * dv : 0.f;
            float v1 = (d2 + 1 < IN_DIM) ? x[(size_t)node * IN_DIM + d2 + 1] * dv : 0.f;
            *(__half2*)(xs + (size_t)node * 8 + d2) = __floats2half2_rn(v0, v1);
        }
    }
}

// ---------------- layer 1 fused: aggregate 6-dim (fp16 table) -> W1+relu -> W2 -> h2s (fp16) ----------------
__global__ void __launch_bounds__(256) k_agg1f(const int2* __restrict__ rowse,
                                               const int* __restrict__ perm,
                                               const __half* __restrict__ xs,
                                               const float* __restrict__ dinv,
                                               const float* __restrict__ b1,
                                               const float* __restrict__ W1,
                                               const float* __restrict__ W2,
                                               __half* __restrict__ h2s, int N) {
    __shared__ float w1[IN_DIM * HID_DIM];
    __shared__ float w2[HID_DIM * LAT_DIM];
    __shared__ float bsh[HID_DIM];
    __shared__ float ash[32][HID_DIM + 1];  // +1 pad: avoid bank conflict
    __shared__ float y[32][8];
    int t = threadIdx.x;
    for (int i = t; i < IN_DIM * HID_DIM; i += 256) w1[i] = W1[i];
    for (int i = t; i < HID_DIM * LAT_DIM; i += 256) w2[i] = W2[i];
    if (t < HID_DIM) bsh[t] = b1[t];
    int nl = t >> 3, p = t & 7;
    int node = blockIdx.x * 32 + nl;
    float acc = 0.f;
    if (node < N) {
        int2 se = rowse[node];
        for (int k0 = se.x; k0 < se.y; k0 += 8) {
            int kk = k0 + p;
            int sp = (kk < se.y) ? __builtin_nontemporal_load(perm + kk) : -1;
#pragma unroll
            for (int j = 0; j < 8; j++) {
                int s = __shfl(sp, j, 8);
                if (s >= 0) acc += __half2float(xs[(size_t)s * 8 + p]);  // L2-hot 16B rows
            }
        }
        acc += __half2float(xs[(size_t)node * 8 + p]);  // self-loop
    }
    y[nl][p] = acc;
    __syncthreads();
    float dv = (node < N) ? dinv[node] : 0.f;
    if (node < N) {
        float yy[IN_DIM];
#pragma unroll
        for (int k = 0; k < IN_DIM; k++) yy[k] = y[nl][k];
        int c0 = p * 4;
#pragma unroll
        for (int q = 0; q < 4; q++) {
            float z = 0.f;
#pragma unroll
            for (int k = 0; k < IN_DIM; k++) z += yy[k] * w1[k * HID_DIM + c0 + q];
            ash[nl][c0 + q] = fmaxf(dv * z + bsh[c0 + q], 0.f);
        }
    }
    __syncthreads();
    if (node < N) {
        int c = p * 2;
        float z0 = 0.f, z1 = 0.f;
#pragma unroll
        for (int k = 0; k < HID_DIM; k++) {
            float a = ash[nl][k];
            z0 += a * w2[k * LAT_DIM + c];
            z1 += a * w2[k * LAT_DIM + c + 1];
        }
        __half2 h = __floats2half2_rn(dv * z0, dv * z1);
        *(__half2*)(h2s + (size_t)node * LAT_DIM + c) = h;
    }
}

// ---------------- layer-2 gather-aggregate + bias -> out: 8 lanes/node, fp16 table ----------------
__global__ void k_agg2(const int2* __restrict__ rowse, const int* __restrict__ perm,
                       const __half* __restrict__ h2s, const float* __restrict__ dinv,
                       const float* __restrict__ b2, float* __restrict__ out, int N) {
    int t = blockIdx.x * blockDim.x + threadIdx.x;
    int node = t >> 3, p = t & 7;
    if (node >= N) return;
    int2 se = rowse[node];
    float2 acc = make_float2(0.f, 0.f);
    for (int k0 = se.x; k0 < se.y; k0 += 8) {
        int kk = k0 + p;
        int sp = (kk < se.y) ? __builtin_nontemporal_load(perm + kk) : -1;
#pragma unroll
        for (int j = 0; j < 8; j++) {
            int s = __shfl(sp, j, 8);
            if (s >= 0) {
                __half2 h = *(const __half2*)(h2s + (size_t)s * LAT_DIM + p * 2);
                float2 f = __half22float2(h);
                acc.x += f.x; acc.y += f.y;
            }
        }
    }
    __half2 hh = *(const __half2*)(h2s + (size_t)node * LAT_DIM + p * 2);  // self-loop
    float2 hs = __half22float2(hh);
    float dv = dinv[node];
    float2 bb = *(const float2*)(b2 + p * 2);
    float2 o;
    o.x = dv * (acc.x + hs.x) + bb.x;
    o.y = dv * (acc.y + hs.y) + bb.y;
    *(float2*)(out + (size_t)node * LAT_DIM + p * 2) = o;
}

extern "C" void kernel_launch(void* const* d_in, const int* in_sizes, int n_in,
                              void* d_out, int out_size, void* d_ws, size_t ws_size,
                              hipStream_t stream) {
    const float* x  = (const float*)d_in[0];
    const int*   ei = (const int*)d_in[1];
    const float* W1 = (const float*)d_in[2];
    const float* b1 = (const float*)d_in[3];
    const float* W2 = (const float*)d_in[4];
    const float* b2 = (const float*)d_in[5];
    float* out = (float*)d_out;

    const int N = N_NODES, E = N_EDGES;
    const int* src = ei;       // edge_index[0]
    const int* dst = ei + E;   // edge_index[1]

    // workspace carve (256B aligned)
    char* ws = (char*)d_ws;
    size_t off = 0;
    auto take = [&](size_t bytes) -> void* {
        void* p = ws + off;
        off += (bytes + 255) & ~(size_t)255;
        return p;
    };
    int*    bcur  = (int*)take((size_t)NB * 4);
    int*    bedge = (int*)take((size_t)NB * CAP * 4);
    int*    perm  = (int*)take((size_t)NB * CAP * 4);
    int2*   rowse = (int2*)take((size_t)N * 8);
    float*  dinv  = (float*)take((size_t)N * 4);
    __half* xs    = (__half*)take((size_t)N * 8 * 2);
    __half* h2s   = (__half*)take((size_t)N * LAT_DIM * 2);

    const int B = 256;
    k_init<<<(NB + B - 1) / B, B, 0, stream>>>(bcur);
    k_bplace<<<AB_BLOCKS, PL_T, 0, stream>>>(src, dst, bcur, bedge, E);
    k_sort<<<NB, B, 0, stream>>>(bcur, bedge, x, rowse, perm, dinv, xs, N);
    k_agg1f<<<(N + 31) / 32, B, 0, stream>>>(rowse, perm, xs, dinv, b1, W1, W2, h2s, N);
    k_agg2<<<((N * 8) + B - 1) / B, B, 0, stream>>>(rowse, perm, h2s, dinv, b2, out, N);
}